// Round 5
// baseline (134.196 us; speedup 1.0000x reference)
//
#include <hip/hip_runtime.h>
#include <math.h>

typedef unsigned short u16;
typedef unsigned int u32;
typedef __bf16 bf16x8 __attribute__((ext_vector_type(8)));
typedef float f32x4 __attribute__((ext_vector_type(4)));

#define SCALING 0.17677669529663687f   // 32^-0.5
#define LOG2E 1.44269504088896f
#define LOG2_10000 13.287712379549449f

__device__ __forceinline__ u16 f2bf(float f) {
    u32 u; __builtin_memcpy(&u, &f, 4);
    u = u + 0x7FFFu + ((u >> 16) & 1u);
    return (u16)(u >> 16);
}
__device__ __forceinline__ u32 fbits(float f) {
    u32 u; __builtin_memcpy(&u, &f, 4); return u;
}
// pack two f32 -> (bf16(lo) | bf16(hi)<<16), round-half-up via +0x8000
__device__ __forceinline__ u32 pack_bf16(float lo, float hi) {
    return __builtin_amdgcn_perm(fbits(hi) + 0x8000u, fbits(lo) + 0x8000u, 0x07060302u);
}
__device__ __forceinline__ f32x4 mfma16(bf16x8 a, bf16x8 b, f32x4 c) {
    return __builtin_amdgcn_mfma_f32_16x16x32_bf16(a, b, c, 0, 0, 0);
}
__device__ __forceinline__ float decay_l2(int h) {
    return logf(1.0f - exp2f(-2.0f - 0.625f * (float)h)) * LOG2E;
}

// ---- f32->bf16 pre-convert (x: 1024 blk, W: 128 blk) + theta table (128 blk) --
__global__ __launch_bounds__(256) void cvt_kernel(
    const float* __restrict__ x,
    const float* __restrict__ Wq, const float* __restrict__ Wk,
    const float* __restrict__ Wv, const float* __restrict__ Wo,
    u16* __restrict__ xb, u16* __restrict__ wb, float2* __restrict__ tc) {
    int bid = blockIdx.x;
    if (bid >= 1152) {   // theta table: tc[l*32+d] = (cos, d odd? sin : -sin)
        int idx = (bid - 1152) * 256 + threadIdx.x;   // 0..32767
        int l = idx >> 5, d = idx & 31;
        float ang = exp2f(-LOG2_10000 * (1.0f / 15.0f) * (float)(d >> 1));
        float idl = (float)((l >> 5) + (l & 31));
        float sv, cv;
        __sincosf(idl * ang, &sv, &cv);
        tc[idx] = make_float2(cv, (d & 1) ? sv : -sv);
        return;
    }
    const float* src; u16* dst; int off;
    if (bid < 1024) { src = x; dst = xb; off = bid * 2048; }
    else {
        int wsel = (bid - 1024) >> 5;
        src = (wsel == 0) ? Wq : (wsel == 1) ? Wk : (wsel == 2) ? Wv : Wo;
        dst = wb + wsel * 65536;
        off = ((bid - 1024) & 31) * 2048;
    }
    int i = off + threadIdx.x * 8;
    float4 a = *(const float4*)&src[i];
    float4 b = *(const float4*)&src[i + 4];
    union { int4 v; u16 s[8]; } t;
    t.s[0] = f2bf(a.x); t.s[1] = f2bf(a.y); t.s[2] = f2bf(a.z); t.s[3] = f2bf(a.w);
    t.s[4] = f2bf(b.x); t.s[5] = f2bf(b.y); t.s[6] = f2bf(b.z); t.s[7] = f2bf(b.w);
    *(int4*)&dst[i] = t.v;
}

// ---------------- GEMM C[i][e] = sum_j A[i][j] W[e][j]  (all bf16 in) ---------
// modes: 0=q (theta-shift), 1=k (scale+shift), 2=v, 3=plain f32 out
__global__ __launch_bounds__(256) void gemm_bt_kernel(
    const u16* __restrict__ A, const u16* __restrict__ Wb,
    const float2* __restrict__ tc,
    u16* __restrict__ O0, u16* __restrict__ O1, u16* __restrict__ O2,
    float* __restrict__ Of, int mode_base) {
    __shared__ __align__(16) u16 As[64 * 136];
    __shared__ __align__(16) u16 Ws[64 * 136];
    int z = blockIdx.z;
    const u16* W = Wb + z * 65536;
    u16* O = (z == 0) ? O0 : (z == 1) ? O1 : O2;
    int mode = mode_base + z;
    int n0 = blockIdx.x * 64, r0 = blockIdx.y * 64;   // n fast => A row-block L2 reuse
    int tid = threadIdx.x;
    int w = tid >> 6, lane = tid & 63, ln = lane & 15, quad = lane >> 4;
    f32x4 acc[4] = {};
#pragma unroll
    for (int ch = 0; ch < 2; ch++) {
        int k0 = ch * 128;
        if (ch) __syncthreads();
#pragma unroll
        for (int i = 0; i < 4; i++) {
            int c = tid + i * 256;
            int row = c >> 4, seg = c & 15;
            *(int4*)&As[row * 136 + seg * 8] = *(const int4*)&A[(long)(r0 + row) * 256 + k0 + seg * 8];
            *(int4*)&Ws[row * 136 + seg * 8] = *(const int4*)&W[(long)(n0 + row) * 256 + k0 + seg * 8];
        }
        __syncthreads();
#pragma unroll
        for (int kt = 0; kt < 4; kt++) {
            bf16x8 a = *(const bf16x8*)&As[(w * 16 + ln) * 136 + kt * 32 + quad * 8];
#pragma unroll
            for (int nt = 0; nt < 4; nt++) {
                bf16x8 b = *(const bf16x8*)&Ws[(nt * 16 + ln) * 136 + kt * 32 + quad * 8];
                acc[nt] = mfma16(a, b, acc[nt]);
            }
        }
    }
    int rowg = r0 + w * 16 + quad * 4;   // C row = quad*4 + reg
    if (mode == 3) {
#pragma unroll
        for (int nt = 0; nt < 4; nt++) {
            int e = n0 + nt * 16 + ln;
#pragma unroll
            for (int r = 0; r < 4; r++)
                Of[(long)(rowg + r) * 256 + e] = acc[nt][r];
        }
        return;
    }
    float scl = (mode == 1) ? SCALING : 1.0f;
#pragma unroll
    for (int nt = 0; nt < 4; nt++) {
        int e = n0 + nt * 16 + ln;
        int d = e & 31, hh = e >> 5;
#pragma unroll
        for (int r = 0; r < 4; r++) {
            int gi = rowg + r;
            int b = gi >> 10, l = gi & 1023;
            float v = acc[nt][r] * scl;
            float p = __shfl_xor(v, 1);   // partner col e^1, same row
            float res;
            if (mode == 2) {
                res = v;
            } else {
                float2 sc = tc[l * 32 + d];
                res = v * sc.x + p * sc.y;
            }
            O[(((long)(b * 8 + hh)) * 1024 + l) * 32 + d] = f2bf(res);
        }
    }
}

// ------- fused retention + LN + GELU: 8 waves, kk-split halves per wave -------
__global__ __launch_bounds__(512) void attn_kernel(
    const u16* __restrict__ qr, const u16* __restrict__ kr, const u16* __restrict__ vr,
    const float* __restrict__ lng, const float* __restrict__ lnb,
    u16* __restrict__ out) {
    __shared__ __align__(16) u16 Qs[64 * 40];
    __shared__ __align__(16) u16 Ks[2][64 * 40];
    __shared__ __align__(16) u32 VtW[2][32 * 36];   // V^T packed dwords [d][kkpair]
    __shared__ __align__(16) u32 PsW[8][16 * 20];   // per-wave half P^T [q][kkpair]
    __shared__ float Tt[64];
    __shared__ float Ss[32];
    __shared__ float lngS[32], lnbS[32];
    int b = blockIdx.z, h = blockIdx.y, q0 = blockIdx.x * 64;
    int tid = threadIdx.x, w = tid >> 6, lane = tid & 63, ln = lane & 15, quad = lane >> 4;
    int wa = w & 3;       // q-group
    int half = w >> 2;    // 0: nt{0,1}/chunk0 ; 1: nt{2,3}/chunk1
    long bh = b * 8 + h;
    const u16* qb = qr + bh * 32768;
    const u16* kb = kr + bh * 32768;
    const u16* vb = vr + bh * 32768;
    float dec = decay_l2(h);
    if (tid < 256) {   // stage Q
        int row = tid >> 2, seg = tid & 3;
        *(int4*)&Qs[row * 40 + seg * 8] = *(const int4*)&qb[(q0 + row) * 32 + seg * 8];
    }
    if (tid < 63) Tt[tid] = exp2f(dec * (float)tid);
    if (tid >= 64 && tid < 96) { lngS[tid - 64] = lng[tid - 64]; lnbS[tid - 64] = lnb[tid - 64]; }
    // staging geometry: waves 0-3 stage K, waves 4-7 stage V
    int krow = tid >> 2, kseg = tid & 3;          // valid for tid<256
    int vt = tid - 256, vp = vt >> 3, vseg = vt & 7;
    int4 kreg; int2 v0, v1;
    if (tid < 256) {
        kreg = *(const int4*)&kb[(long)krow * 32 + kseg * 8];
    } else {
        v0 = *(const int2*)&vb[(long)(vp * 2) * 32 + vseg * 4];
        v1 = *(const int2*)&vb[(long)(vp * 2 + 1) * 32 + vseg * 4];
    }
    __syncthreads();   // Tt, Qs ready
    if (tid < 32) {
        float s = 0.0f;
#pragma unroll
        for (int b2 = 0; b2 < 32; b2++) s += Tt[abs(tid - b2)];
        Ss[tid] = s;
    }
    if (tid < 256) {
        *(int4*)&Ks[0][krow * 40 + kseg * 8] = kreg;
        kreg = *(const int4*)&kb[(long)(64 + krow) * 32 + kseg * 8];
    } else {
        VtW[0][(vseg * 4 + 0) * 36 + vp] = __builtin_amdgcn_perm(v1.x, v0.x, 0x05040100u);
        VtW[0][(vseg * 4 + 1) * 36 + vp] = __builtin_amdgcn_perm(v1.x, v0.x, 0x07060302u);
        VtW[0][(vseg * 4 + 2) * 36 + vp] = __builtin_amdgcn_perm(v1.y, v0.y, 0x05040100u);
        VtW[0][(vseg * 4 + 3) * 36 + vp] = __builtin_amdgcn_perm(v1.y, v0.y, 0x07060302u);
        v0 = *(const int2*)&vb[(long)(64 + vp * 2) * 32 + vseg * 4];
        v1 = *(const int2*)&vb[(long)(64 + vp * 2 + 1) * 32 + vseg * 4];
    }
    __syncthreads();   // Ss + buf0 ready
    int q = q0 + wa * 16 + ln;
    int q1i = q >> 5, q2i = q & 31;
    float rqv = rsqrtf(Ss[q1i] * Ss[q2i]);
    bf16x8 aq = *(const bf16x8*)&Qs[(wa * 16 + ln) * 40 + quad * 8];   // Q B-frag
    float bt[2][4];
#pragma unroll
    for (int s2 = 0; s2 < 2; s2++)
#pragma unroll
        for (int r = 0; r < 4; r++)
            bt[s2][r] = Tt[abs(q2i - (s2 * 16 + quad * 4 + r))];
    f32x4 accO0 = {}, accO1 = {};
    float den = 0.0f;
    u32* psw = &PsW[w][0];
    for (int kt = 0; kt < 16; kt++) {
        int cur = kt & 1;
        float aa = Tt[abs(q1i - 2 * kt - half)] * rqv;   // k1 = 2*kt + half
        const u16* ksb = &Ks[cur][0];
        const u32* vtb = &VtW[cur][0];
#pragma unroll
        for (int j = 0; j < 2; j++) {
            int nt = 2 * half + j;
            bf16x8 ak = *(const bf16x8*)&ksb[(nt * 16 + ln) * 40 + quad * 8];
            f32x4 s = mfma16(ak, aq, (f32x4){0.f, 0.f, 0.f, 0.f});   // S^T rows kk, col q
            float p0 = s[0] * aa * bt[j][0];
            float p1 = s[1] * aa * bt[j][1];
            float p2 = s[2] * aa * bt[j][2];
            float p3 = s[3] * aa * bt[j][3];
            den += fabsf(p0); den += fabsf(p1); den += fabsf(p2); den += fabsf(p3);
            int2 pw;
            pw.x = (int)pack_bf16(p0, p1);
            pw.y = (int)pack_bf16(p2, p3);
            *(int2*)&psw[ln * 20 + j * 8 + quad * 2] = pw;   // wave-private
        }
        {   // PV for this wave's chunk c = half
            bf16x8 bp  = *(const bf16x8*)&psw[ln * 20 + quad * 4];
            bf16x8 av0 = *(const bf16x8*)&vtb[(ln)      * 36 + half * 16 + quad * 4];
            bf16x8 av1 = *(const bf16x8*)&vtb[(16 + ln) * 36 + half * 16 + quad * 4];
            accO0 = mfma16(av0, bp, accO0);
            accO1 = mfma16(av1, bp, accO1);
        }
        if (kt < 15) {
            int nb = 1 - cur;
            if (tid < 256) {
                *(int4*)&Ks[nb][krow * 40 + kseg * 8] = kreg;
                if (kt < 14)
                    kreg = *(const int4*)&kb[(long)((kt + 2) * 64 + krow) * 32 + kseg * 8];
            } else {
                VtW[nb][(vseg * 4 + 0) * 36 + vp] = __builtin_amdgcn_perm(v1.x, v0.x, 0x05040100u);
                VtW[nb][(vseg * 4 + 1) * 36 + vp] = __builtin_amdgcn_perm(v1.x, v0.x, 0x07060302u);
                VtW[nb][(vseg * 4 + 2) * 36 + vp] = __builtin_amdgcn_perm(v1.y, v0.y, 0x05040100u);
                VtW[nb][(vseg * 4 + 3) * 36 + vp] = __builtin_amdgcn_perm(v1.y, v0.y, 0x07060302u);
                if (kt < 14) {
                    int t2 = (kt + 2) * 64;
                    v0 = *(const int2*)&vb[(long)(t2 + vp * 2) * 32 + vseg * 4];
                    v1 = *(const int2*)&vb[(long)(t2 + vp * 2 + 1) * 32 + vseg * 4];
                }
            }
            __syncthreads();
        }
    }
    // reduce den over this wave's quads
    den += __shfl_xor(den, 16);
    den += __shfl_xor(den, 32);
    __syncthreads();
    float* cmb = (float*)&PsW[0][0];   // reuse: 4 waves x 64 lanes x 9 f32 = 9216 B
    if (half == 1) {
        float* cp = cmb + (wa * 64 + lane) * 9;
#pragma unroll
        for (int r = 0; r < 4; r++) { cp[r] = accO0[r]; cp[4 + r] = accO1[r]; }
        cp[8] = den;
    }
    __syncthreads();
    if (half == 0) {
        const float* cp = cmb + (wa * 64 + lane) * 9;
#pragma unroll
        for (int r = 0; r < 4; r++) { accO0[r] += cp[r]; accO1[r] += cp[4 + r]; }
        den += cp[8];
        float id = 1.0f / fminf(fmaxf(den, 1.0f), 50000.0f);
        float o[8];
#pragma unroll
        for (int r = 0; r < 4; r++) { o[r] = accO0[r] * id; o[4 + r] = accO1[r] * id; }
        float s1 = 0.0f, s2 = 0.0f;
#pragma unroll
        for (int i = 0; i < 8; i++) { s1 += o[i]; s2 += o[i] * o[i]; }
        s1 += __shfl_xor(s1, 16); s1 += __shfl_xor(s1, 32);
        s2 += __shfl_xor(s2, 16); s2 += __shfl_xor(s2, 32);
        float mean = s1 * (1.0f / 32.0f);
        float var = s2 * (1.0f / 32.0f) - mean * mean;
        float rstd = rsqrtf(var + 1e-5f);
        float xg[8];
#pragma unroll
        for (int nv = 0; nv < 2; nv++)
#pragma unroll
            for (int r = 0; r < 4; r++) {
                int d = nv * 16 + quad * 4 + r;
                float xv = (o[nv * 4 + r] - mean) * rstd * lngS[d] + lnbS[d];
                xg[nv * 4 + r] = 0.5f * xv * (1.0f + erff(xv * 0.70710678118654752f));
            }
        u16* orow = out + ((long)(b * 1024 + q)) * 256 + h * 32;
        int2 st0, st1;
        st0.x = (int)pack_bf16(xg[0], xg[1]); st0.y = (int)pack_bf16(xg[2], xg[3]);
        st1.x = (int)pack_bf16(xg[4], xg[5]); st1.y = (int)pack_bf16(xg[6], xg[7]);
        *(int2*)&orow[quad * 4] = st0;
        *(int2*)&orow[16 + quad * 4] = st1;
    }
}

extern "C" void kernel_launch(void* const* d_in, const int* in_sizes, int n_in,
                              void* d_out, int out_size, void* d_ws, size_t ws_size,
                              hipStream_t stream) {
    const float* x   = (const float*)d_in[0];
    const float* Wq  = (const float*)d_in[1];
    const float* Wk  = (const float*)d_in[2];
    const float* Wv  = (const float*)d_in[3];
    const float* Wo  = (const float*)d_in[4];
    const float* lng = (const float*)d_in[5];
    const float* lnb = (const float*)d_in[6];
    float* outp = (float*)d_out;

    u16* xb   = (u16*)d_ws;             // [B*L][256] bf16
    u16* wb   = xb + 2097152;           // Wq|Wk|Wv|Wo bf16, 65536 each
    u16* qr   = wb + 262144;            // [B][H][L][32] bf16
    u16* kr   = qr + 2097152;
    u16* vr   = kr + 2097152;
    u16* attn = vr + 2097152;           // [B*L][256] bf16
    float2* tc = (float2*)(attn + 2097152);   // [L][32] (cos, +/-sin), 256 KB

    cvt_kernel<<<1280, 256, 0, stream>>>(x, Wq, Wk, Wv, Wo, xb, wb, tc);
    gemm_bt_kernel<<<dim3(4, 128, 3), 256, 0, stream>>>(xb, wb, tc, qr, kr, vr, nullptr, 0);
    attn_kernel<<<dim3(16, 8, 8), 512, 0, stream>>>(qr, kr, vr, lng, lnb, attn);
    gemm_bt_kernel<<<dim3(4, 128, 1), 256, 0, stream>>>(attn, wb + 3 * 65536, tc, nullptr, nullptr, nullptr, outp, 3);
}

// Round 6
// 121.598 us; speedup vs baseline: 1.1036x; 1.1036x over previous
//
#include <hip/hip_runtime.h>
#include <math.h>

typedef unsigned short u16;
typedef unsigned int u32;
typedef __bf16 bf16x8 __attribute__((ext_vector_type(8)));
typedef float f32x4 __attribute__((ext_vector_type(4)));

#define SCALING 0.17677669529663687f   // 32^-0.5
#define LOG2E 1.44269504088896f
#define LOG2_10000 13.287712379549449f

__device__ __forceinline__ u16 f2bf(float f) {
    u32 u; __builtin_memcpy(&u, &f, 4);
    u = u + 0x7FFFu + ((u >> 16) & 1u);
    return (u16)(u >> 16);
}
__device__ __forceinline__ u32 fbits(float f) {
    u32 u; __builtin_memcpy(&u, &f, 4); return u;
}
// pack two f32 -> (bf16(lo) | bf16(hi)<<16), round-half-up via +0x8000
__device__ __forceinline__ u32 pack_bf16(float lo, float hi) {
    return __builtin_amdgcn_perm(fbits(hi) + 0x8000u, fbits(lo) + 0x8000u, 0x07060302u);
}
__device__ __forceinline__ f32x4 mfma16(bf16x8 a, bf16x8 b, f32x4 c) {
    return __builtin_amdgcn_mfma_f32_16x16x32_bf16(a, b, c, 0, 0, 0);
}
__device__ __forceinline__ float decay_l2(int h) {
    return logf(1.0f - exp2f(-2.0f - 0.625f * (float)h)) * LOG2E;
}

// ---- f32->bf16 pre-convert (x: 1024 blk, W: 128 blk) + theta table (128 blk) --
__global__ __launch_bounds__(256) void cvt_kernel(
    const float* __restrict__ x,
    const float* __restrict__ Wq, const float* __restrict__ Wk,
    const float* __restrict__ Wv, const float* __restrict__ Wo,
    u16* __restrict__ xb, u16* __restrict__ wb, float2* __restrict__ tc) {
    int bid = blockIdx.x;
    if (bid >= 1152) {   // theta table: tc[l*32+d] = (cos, d odd? sin : -sin)
        int idx = (bid - 1152) * 256 + threadIdx.x;   // 0..32767
        int l = idx >> 5, d = idx & 31;
        float ang = exp2f(-LOG2_10000 * (1.0f / 15.0f) * (float)(d >> 1));
        float idl = (float)((l >> 5) + (l & 31));
        float sv, cv;
        __sincosf(idl * ang, &sv, &cv);
        tc[idx] = make_float2(cv, (d & 1) ? sv : -sv);
        return;
    }
    const float* src; u16* dst; int off;
    if (bid < 1024) { src = x; dst = xb; off = bid * 2048; }
    else {
        int wsel = (bid - 1024) >> 5;
        src = (wsel == 0) ? Wq : (wsel == 1) ? Wk : (wsel == 2) ? Wv : Wo;
        dst = wb + wsel * 65536;
        off = ((bid - 1024) & 31) * 2048;
    }
    int i = off + threadIdx.x * 8;
    float4 a = *(const float4*)&src[i];
    float4 b = *(const float4*)&src[i + 4];
    union { int4 v; u16 s[8]; } t;
    t.s[0] = f2bf(a.x); t.s[1] = f2bf(a.y); t.s[2] = f2bf(a.z); t.s[3] = f2bf(a.w);
    t.s[4] = f2bf(b.x); t.s[5] = f2bf(b.y); t.s[6] = f2bf(b.z); t.s[7] = f2bf(b.w);
    *(int4*)&dst[i] = t.v;
}

// ---------------- GEMM C[i][e] = sum_j A[i][j] W[e][j]  (all bf16 in) ---------
// modes: 0=q (theta-shift), 1=k (scale+shift), 2=v, 3=plain f32 out
__global__ __launch_bounds__(256) void gemm_bt_kernel(
    const u16* __restrict__ A, const u16* __restrict__ Wb,
    const float2* __restrict__ tc,
    u16* __restrict__ O0, u16* __restrict__ O1, u16* __restrict__ O2,
    float* __restrict__ Of, int mode_base) {
    __shared__ __align__(16) u16 As[64 * 136];
    __shared__ __align__(16) u16 Ws[64 * 136];
    int z = blockIdx.z;
    const u16* W = Wb + z * 65536;
    u16* O = (z == 0) ? O0 : (z == 1) ? O1 : O2;
    int mode = mode_base + z;
    int n0 = blockIdx.x * 64, r0 = blockIdx.y * 64;   // n fast => A row-block L2 reuse
    int tid = threadIdx.x;
    int w = tid >> 6, lane = tid & 63, ln = lane & 15, quad = lane >> 4;
    f32x4 acc[4] = {};
#pragma unroll
    for (int ch = 0; ch < 2; ch++) {
        int k0 = ch * 128;
        if (ch) __syncthreads();
#pragma unroll
        for (int i = 0; i < 4; i++) {
            int c = tid + i * 256;
            int row = c >> 4, seg = c & 15;
            *(int4*)&As[row * 136 + seg * 8] = *(const int4*)&A[(long)(r0 + row) * 256 + k0 + seg * 8];
            *(int4*)&Ws[row * 136 + seg * 8] = *(const int4*)&W[(long)(n0 + row) * 256 + k0 + seg * 8];
        }
        __syncthreads();
#pragma unroll
        for (int kt = 0; kt < 4; kt++) {
            bf16x8 a = *(const bf16x8*)&As[(w * 16 + ln) * 136 + kt * 32 + quad * 8];
#pragma unroll
            for (int nt = 0; nt < 4; nt++) {
                bf16x8 b = *(const bf16x8*)&Ws[(nt * 16 + ln) * 136 + kt * 32 + quad * 8];
                acc[nt] = mfma16(a, b, acc[nt]);
            }
        }
    }
    int rowg = r0 + w * 16 + quad * 4;   // C row = quad*4 + reg
    if (mode == 3) {
#pragma unroll
        for (int nt = 0; nt < 4; nt++) {
            int e = n0 + nt * 16 + ln;
#pragma unroll
            for (int r = 0; r < 4; r++)
                Of[(long)(rowg + r) * 256 + e] = acc[nt][r];
        }
        return;
    }
    float scl = (mode == 1) ? SCALING : 1.0f;
#pragma unroll
    for (int nt = 0; nt < 4; nt++) {
        int e = n0 + nt * 16 + ln;
        int d = e & 31, hh = e >> 5;
#pragma unroll
        for (int r = 0; r < 4; r++) {
            int gi = rowg + r;
            int b = gi >> 10, l = gi & 1023;
            float v = acc[nt][r] * scl;
            float p = __shfl_xor(v, 1);   // partner col e^1, same row
            float res;
            if (mode == 2) {
                res = v;
            } else {
                float2 sc = tc[l * 32 + d];
                res = v * sc.x + p * sc.y;
            }
            O[(((long)(b * 8 + hh)) * 1024 + l) * 32 + d] = f2bf(res);
        }
    }
}

// ------- retention partial: half the k-range per block, f32 partials out ------
// grid (16, 8, 16): x=q-tile, y=h, z = b*2 + kh. 256 threads.
__global__ __launch_bounds__(256) void attn_part_kernel(
    const u16* __restrict__ qr, const u16* __restrict__ kr, const u16* __restrict__ vr,
    float* __restrict__ pO, float* __restrict__ pD) {
    __shared__ __align__(16) char smem[29056];
    u16* Qs  = (u16*)smem;                    // 64*40 u16 = 5120 B (overlays PsW)
    u32* PsW = (u32*)smem;                    // 4 * 16*36 dw = 9216 B
    u16* Ks0 = (u16*)(smem + 9216);           // 64*40 u16
    u16* Ks1 = (u16*)(smem + 14336);
    u32* Vt0 = (u32*)(smem + 19456);          // 32*36 dw = 4608 B
    u32* Vt1 = (u32*)(smem + 24064);
    float* Tt = (float*)(smem + 28672);       // 64 f32
    float* Ss = (float*)(smem + 28928);       // 32 f32
    int z = blockIdx.z, b = z >> 1, kh = z & 1, h = blockIdx.y, q0 = blockIdx.x * 64;
    int tid = threadIdx.x, w = tid >> 6, lane = tid & 63, ln = lane & 15, quad = lane >> 4;
    long bh = b * 8 + h;
    const u16* qb = qr + bh * 32768;
    const u16* kb = kr + bh * 32768 + kh * 16384;   // rows kh*512
    const u16* vb = vr + bh * 32768 + kh * 16384;
    float dec = decay_l2(h);
    {   // stage Q
        int row = tid >> 2, seg = tid & 3;
        *(int4*)&Qs[row * 40 + seg * 8] = *(const int4*)&qb[(q0 + row) * 32 + seg * 8];
    }
    if (tid < 63) Tt[tid] = exp2f(dec * (float)tid);
    // staging geometry
    int krow = tid >> 2, kseg = tid & 3;
    int vp = tid >> 3, vseg = tid & 7;
    int4 kreg = *(const int4*)&kb[(long)krow * 32 + kseg * 8];
    int2 v0 = *(const int2*)&vb[(long)(vp * 2) * 32 + vseg * 4];
    int2 v1 = *(const int2*)&vb[(long)(vp * 2 + 1) * 32 + vseg * 4];
    __syncthreads();   // Qs + Tt ready
    // read Q fragment BEFORE PsW (overlaid on Qs) can be written
    bf16x8 aq = *(const bf16x8*)&Qs[(w * 16 + ln) * 40 + quad * 8];
    int q = q0 + w * 16 + ln;
    int q1i = q >> 5, q2i = q & 31;
    float bt[2][4];
#pragma unroll
    for (int s2 = 0; s2 < 2; s2++)
#pragma unroll
        for (int r = 0; r < 4; r++)
            bt[s2][r] = Tt[abs(q2i - (s2 * 16 + quad * 4 + r))];
    if (tid < 32) {
        float s = 0.0f;
#pragma unroll
        for (int b2 = 0; b2 < 32; b2++) s += Tt[abs(tid - b2)];
        Ss[tid] = s;
    }
    // write tile 0 to buf 0, prefetch tile 1
    *(int4*)&Ks0[krow * 40 + kseg * 8] = kreg;
    Vt0[(vseg * 4 + 0) * 36 + vp] = __builtin_amdgcn_perm(v1.x, v0.x, 0x05040100u);
    Vt0[(vseg * 4 + 1) * 36 + vp] = __builtin_amdgcn_perm(v1.x, v0.x, 0x07060302u);
    Vt0[(vseg * 4 + 2) * 36 + vp] = __builtin_amdgcn_perm(v1.y, v0.y, 0x05040100u);
    Vt0[(vseg * 4 + 3) * 36 + vp] = __builtin_amdgcn_perm(v1.y, v0.y, 0x07060302u);
    kreg = *(const int4*)&kb[(long)(64 + krow) * 32 + kseg * 8];
    v0 = *(const int2*)&vb[(long)(64 + vp * 2) * 32 + vseg * 4];
    v1 = *(const int2*)&vb[(long)(64 + vp * 2 + 1) * 32 + vseg * 4];
    __syncthreads();   // Ss + buf0 ready; all aq reads done
    float rqv = rsqrtf(Ss[q1i] * Ss[q2i]);
    f32x4 accO0 = {}, accO1 = {};
    float den = 0.0f;
    u32* psw = &PsW[w * 16 * 36];
    for (int kt = 0; kt < 8; kt++) {
        int cur = kt & 1;
        int ktg = kh * 8 + kt;
        float a0 = Tt[abs(q1i - 2 * ktg)] * rqv;
        float a1 = Tt[abs(q1i - 2 * ktg - 1)] * rqv;
        const u16* ksb = cur ? Ks1 : Ks0;
        const u32* vtb = cur ? Vt1 : Vt0;
#pragma unroll
        for (int nt = 0; nt < 4; nt++) {
            bf16x8 ak = *(const bf16x8*)&ksb[(nt * 16 + ln) * 40 + quad * 8];
            f32x4 s = mfma16(ak, aq, (f32x4){0.f, 0.f, 0.f, 0.f});   // S^T rows kk, col q
            float aa = (nt & 2) ? a1 : a0;
            float p0 = s[0] * aa * bt[nt & 1][0];
            float p1 = s[1] * aa * bt[nt & 1][1];
            float p2 = s[2] * aa * bt[nt & 1][2];
            float p3 = s[3] * aa * bt[nt & 1][3];
            den += fabsf(p0); den += fabsf(p1); den += fabsf(p2); den += fabsf(p3);
            int2 pw;
            pw.x = (int)pack_bf16(p0, p1);
            pw.y = (int)pack_bf16(p2, p3);
            *(int2*)&psw[ln * 36 + nt * 8 + quad * 2] = pw;   // wave-private
        }
#pragma unroll
        for (int c = 0; c < 2; c++) {
            bf16x8 bp  = *(const bf16x8*)&psw[ln * 36 + c * 16 + quad * 4];
            bf16x8 av0 = *(const bf16x8*)&vtb[(ln)      * 36 + c * 16 + quad * 4];
            bf16x8 av1 = *(const bf16x8*)&vtb[(16 + ln) * 36 + c * 16 + quad * 4];
            accO0 = mfma16(av0, bp, accO0);
            accO1 = mfma16(av1, bp, accO1);
        }
        if (kt < 7) {
            u16* ksn = cur ? Ks0 : Ks1;
            u32* vtn = cur ? Vt0 : Vt1;
            *(int4*)&ksn[krow * 40 + kseg * 8] = kreg;
            vtn[(vseg * 4 + 0) * 36 + vp] = __builtin_amdgcn_perm(v1.x, v0.x, 0x05040100u);
            vtn[(vseg * 4 + 1) * 36 + vp] = __builtin_amdgcn_perm(v1.x, v0.x, 0x07060302u);
            vtn[(vseg * 4 + 2) * 36 + vp] = __builtin_amdgcn_perm(v1.y, v0.y, 0x05040100u);
            vtn[(vseg * 4 + 3) * 36 + vp] = __builtin_amdgcn_perm(v1.y, v0.y, 0x07060302u);
            if (kt < 6) {
                int t2 = (kt + 2) * 64;
                kreg = *(const int4*)&kb[(long)(t2 + krow) * 32 + kseg * 8];
                v0 = *(const int2*)&vb[(long)(t2 + vp * 2) * 32 + vseg * 4];
                v1 = *(const int2*)&vb[(long)(t2 + vp * 2 + 1) * 32 + vseg * 4];
            }
            __syncthreads();
        }
    }
    // reduce den over quads, then store partials
    den += __shfl_xor(den, 16);
    den += __shfl_xor(den, 32);
    long base = ((long)(bh * 2 + kh) * 1024 + q) * 32;
    *(f32x4*)&pO[base + quad * 4] = accO0;
    *(f32x4*)&pO[base + 16 + quad * 4] = accO1;
    if (quad == 0) pD[(bh * 2 + kh) * 1024 + q] = den;
}

// ------- combine halves + den-divide + LN + GELU -> bf16 attn -----------------
// grid 2048 x 256: 32 rows/block, 8 lanes per row (4 d each)
__global__ __launch_bounds__(256) void combine_kernel(
    const float* __restrict__ pO, const float* __restrict__ pD,
    const float* __restrict__ lng, const float* __restrict__ lnb,
    u16* __restrict__ attn) {
    int tid = threadIdx.x;
    int row = blockIdx.x * 32 + (tid >> 3);   // (bh,q) row 0..65535
    int l8 = tid & 7;
    int q = row & 1023, bh = row >> 10;
    long i0 = ((long)(bh * 2) * 1024 + q) * 32 + l8 * 4;
    f32x4 a = *(const f32x4*)&pO[i0];
    f32x4 c = *(const f32x4*)&pO[i0 + 32768];   // kh=1 block: +1024*32
    float den = pD[(bh * 2) * 1024 + q] + pD[(bh * 2 + 1) * 1024 + q];
    float id = 1.0f / fminf(fmaxf(den, 1.0f), 50000.0f);
    float o[4]; float s1 = 0.0f, s2 = 0.0f;
#pragma unroll
    for (int r = 0; r < 4; r++) {
        o[r] = (a[r] + c[r]) * id;
        s1 += o[r]; s2 += o[r] * o[r];
    }
#pragma unroll
    for (int m = 1; m < 8; m <<= 1) { s1 += __shfl_xor(s1, m); s2 += __shfl_xor(s2, m); }
    float mean = s1 * (1.0f / 32.0f);
    float var = s2 * (1.0f / 32.0f) - mean * mean;
    float rstd = rsqrtf(var + 1e-5f);
    float xg[4];
#pragma unroll
    for (int r = 0; r < 4; r++) {
        int d = l8 * 4 + r;
        float xv = (o[r] - mean) * rstd * lng[d] + lnb[d];
        xg[r] = 0.5f * xv * (1.0f + erff(xv * 0.70710678118654752f));
    }
    int b = bh >> 3, h = bh & 7;
    int2 st;
    st.x = (int)pack_bf16(xg[0], xg[1]);
    st.y = (int)pack_bf16(xg[2], xg[3]);
    *(int2*)&attn[((long)(b * 1024 + q)) * 256 + h * 32 + l8 * 4] = st;
}

extern "C" void kernel_launch(void* const* d_in, const int* in_sizes, int n_in,
                              void* d_out, int out_size, void* d_ws, size_t ws_size,
                              hipStream_t stream) {
    const float* x   = (const float*)d_in[0];
    const float* Wq  = (const float*)d_in[1];
    const float* Wk  = (const float*)d_in[2];
    const float* Wv  = (const float*)d_in[3];
    const float* Wo  = (const float*)d_in[4];
    const float* lng = (const float*)d_in[5];
    const float* lnb = (const float*)d_in[6];
    float* outp = (float*)d_out;

    u16* xb   = (u16*)d_ws;             // [B*L][256] bf16, 4 MB
    u16* wb   = xb + 2097152;           // Wq|Wk|Wv|Wo bf16, 0.5 MB
    u16* qr   = wb + 262144;            // [B][H][L][32] bf16, 4 MB
    u16* kr   = qr + 2097152;
    u16* vr   = kr + 2097152;
    u16* attn = vr + 2097152;           // [B*L][256] bf16, 4 MB
    float2* tc = (float2*)(attn + 2097152);   // [L][32], 256 KB
    float* pO = (float*)(tc + 32768);   // [bh*2+kh][1024][32] f32, 16 MB
    float* pD = pO + 4194304;           // [bh*2+kh][1024] f32, 0.5 MB

    cvt_kernel<<<1280, 256, 0, stream>>>(x, Wq, Wk, Wv, Wo, xb, wb, tc);
    gemm_bt_kernel<<<dim3(4, 128, 3), 256, 0, stream>>>(xb, wb, tc, qr, kr, vr, nullptr, 0);
    attn_part_kernel<<<dim3(16, 8, 16), 256, 0, stream>>>(qr, kr, vr, pO, pD);
    combine_kernel<<<2048, 256, 0, stream>>>(pO, pD, lng, lnb, attn);
    gemm_bt_kernel<<<dim3(4, 128, 1), 256, 0, stream>>>(attn, wb + 3 * 65536, tc, nullptr, nullptr, nullptr, outp, 3);
}

// Round 7
// 120.460 us; speedup vs baseline: 1.1140x; 1.0094x over previous
//
#include <hip/hip_runtime.h>
#include <math.h>

typedef unsigned short u16;
typedef unsigned int u32;
typedef unsigned long long u64;
typedef __bf16 bf16x8 __attribute__((ext_vector_type(8)));
typedef short s16x4 __attribute__((ext_vector_type(4)));
typedef float f32x4 __attribute__((ext_vector_type(4)));

#define SCALING 0.17677669529663687f   // 32^-0.5
#define LOG2E 1.44269504088896f
#define LOG2_10000 13.287712379549449f

__device__ __forceinline__ u16 f2bf(float f) {
    u32 u; __builtin_memcpy(&u, &f, 4);
    u = u + 0x7FFFu + ((u >> 16) & 1u);
    return (u16)(u >> 16);
}
__device__ __forceinline__ u32 fbits(float f) {
    u32 u; __builtin_memcpy(&u, &f, 4); return u;
}
// pack two f32 -> (bf16(lo) | bf16(hi)<<16), round-half-up via +0x8000
__device__ __forceinline__ u32 pack_bf16(float lo, float hi) {
    return __builtin_amdgcn_perm(fbits(hi) + 0x8000u, fbits(lo) + 0x8000u, 0x07060302u);
}
__device__ __forceinline__ f32x4 mfma16(bf16x8 a, bf16x8 b, f32x4 c) {
    return __builtin_amdgcn_mfma_f32_16x16x32_bf16(a, b, c, 0, 0, 0);
}
// K=16 bf16 MFMA: 4 bf16 per lane per operand (2 VGPRs)
__device__ __forceinline__ f32x4 mfma_k16(u64 a, u64 b, f32x4 c) {
#if __has_builtin(__builtin_amdgcn_mfma_f32_16x16x16bf16_1k)
    s16x4 av, bv;
    __builtin_memcpy(&av, &a, 8); __builtin_memcpy(&bv, &b, 8);
    return __builtin_amdgcn_mfma_f32_16x16x16bf16_1k(av, bv, c, 0, 0, 0);
#elif __has_builtin(__builtin_amdgcn_mfma_f32_16x16x16_bf16)
    typedef __bf16 bf16x4_t __attribute__((ext_vector_type(4)));
    bf16x4_t av, bv;
    __builtin_memcpy(&av, &a, 8); __builtin_memcpy(&bv, &b, 8);
    return __builtin_amdgcn_mfma_f32_16x16x16_bf16(av, bv, c, 0, 0, 0);
#else
    f32x4 d = c;
    asm volatile("v_mfma_f32_16x16x16_bf16 %0, %1, %2, %0\n\ts_nop 4"
                 : "+v"(d) : "v"(a), "v"(b));
    return d;
#endif
}
__device__ __forceinline__ float decay_l2(int h) {
    return logf(1.0f - exp2f(-2.0f - 0.625f * (float)h)) * LOG2E;
}

// ---------------- theta table: tc[l*32+d] = (cos, d odd? sin : -sin) ----------
__global__ __launch_bounds__(256) void tc_kernel(float2* __restrict__ tc) {
    int idx = blockIdx.x * 256 + threadIdx.x;   // 0..32767
    int l = idx >> 5, d = idx & 31;
    float ang = exp2f(-LOG2_10000 * (1.0f / 15.0f) * (float)(d >> 1));
    float idl = (float)((l >> 5) + (l & 31));
    float sv, cv;
    __sincosf(idl * ang, &sv, &cv);
    tc[idx] = make_float2(cv, (d & 1) ? sv : -sv);
}

// ---------------- GEMM C[i][e] = sum_j A[i][j] W[e][j] ------------------------
// A f32 (AF32=1) or bf16 (AF32=0); W f32, converted during staging.
// modes: 0=q (theta-shift), 1=k (scale+shift), 2=v, 3=plain f32 out
template<int AF32>
__global__ __launch_bounds__(256) void gemm_bt_kernel(
    const void* __restrict__ Av,
    const float* __restrict__ W0, const float* __restrict__ W1, const float* __restrict__ W2,
    const float2* __restrict__ tc,
    u16* __restrict__ O0, u16* __restrict__ O1, u16* __restrict__ O2,
    float* __restrict__ Of, int mode_base) {
    __shared__ __align__(16) u16 As[64 * 136];
    __shared__ __align__(16) u16 Ws[64 * 136];
    int z = blockIdx.z;
    const float* W = (z == 0) ? W0 : (z == 1) ? W1 : W2;
    u16* O = (z == 0) ? O0 : (z == 1) ? O1 : O2;
    int mode = mode_base + z;
    int n0 = blockIdx.x * 64, r0 = blockIdx.y * 64;   // n fast => A row-block L2 reuse
    int tid = threadIdx.x;
    int w = tid >> 6, lane = tid & 63, ln = lane & 15, quad = lane >> 4;
    f32x4 acc[4] = {};
#pragma unroll
    for (int ch = 0; ch < 2; ch++) {
        int k0 = ch * 128;
        if (ch) __syncthreads();
        // stage W (f32 -> bf16)
#pragma unroll
        for (int i = 0; i < 8; i++) {
            int c = tid + i * 256;
            int row = c >> 5, seg = c & 31;
            float4 wv = *(const float4*)&W[(long)(n0 + row) * 256 + k0 + seg * 4];
            union { int2 v; u16 s[4]; } t;
            t.s[0] = f2bf(wv.x); t.s[1] = f2bf(wv.y); t.s[2] = f2bf(wv.z); t.s[3] = f2bf(wv.w);
            *(int2*)&Ws[row * 136 + seg * 4] = t.v;
        }
        if (AF32) {
            const float* A = (const float*)Av;
#pragma unroll
            for (int i = 0; i < 8; i++) {
                int c = tid + i * 256;
                int row = c >> 5, seg = c & 31;
                float4 av = *(const float4*)&A[(long)(r0 + row) * 256 + k0 + seg * 4];
                union { int2 v; u16 s[4]; } t;
                t.s[0] = f2bf(av.x); t.s[1] = f2bf(av.y); t.s[2] = f2bf(av.z); t.s[3] = f2bf(av.w);
                *(int2*)&As[row * 136 + seg * 4] = t.v;
            }
        } else {
            const u16* A = (const u16*)Av;
#pragma unroll
            for (int i = 0; i < 4; i++) {
                int c = tid + i * 256;
                int row = c >> 4, seg = c & 15;
                *(int4*)&As[row * 136 + seg * 8] = *(const int4*)&A[(long)(r0 + row) * 256 + k0 + seg * 8];
            }
        }
        __syncthreads();
#pragma unroll
        for (int kt = 0; kt < 4; kt++) {
            bf16x8 a = *(const bf16x8*)&As[(w * 16 + ln) * 136 + kt * 32 + quad * 8];
#pragma unroll
            for (int nt = 0; nt < 4; nt++) {
                bf16x8 b = *(const bf16x8*)&Ws[(nt * 16 + ln) * 136 + kt * 32 + quad * 8];
                acc[nt] = mfma16(a, b, acc[nt]);
            }
        }
    }
    int rowg = r0 + w * 16 + quad * 4;   // C row = quad*4 + reg
    if (mode == 3) {
#pragma unroll
        for (int nt = 0; nt < 4; nt++) {
            int e = n0 + nt * 16 + ln;
#pragma unroll
            for (int r = 0; r < 4; r++)
                Of[(long)(rowg + r) * 256 + e] = acc[nt][r];
        }
        return;
    }
    float scl = (mode == 1) ? SCALING : 1.0f;
#pragma unroll
    for (int nt = 0; nt < 4; nt++) {
        int e = n0 + nt * 16 + ln;
        int d = e & 31, hh = e >> 5;
#pragma unroll
        for (int r = 0; r < 4; r++) {
            int gi = rowg + r;
            int b = gi >> 10, l = gi & 1023;
            float v = acc[nt][r] * scl;
            float p = __shfl_xor(v, 1);   // partner col e^1, same row
            float res;
            if (mode == 2) {
                res = v;
            } else {
                float2 sc = tc[l * 32 + d];
                res = v * sc.x + p * sc.y;
            }
            O[(((long)(b * 8 + hh)) * 1024 + l) * 32 + d] = f2bf(res);
        }
    }
}

// ---- fused retention + LN + GELU: register P -> K=16 PV MFMA (no P in LDS) ---
__global__ __launch_bounds__(256) void attn_kernel(
    const u16* __restrict__ qr, const u16* __restrict__ kr, const u16* __restrict__ vr,
    const float* __restrict__ lng, const float* __restrict__ lnb,
    u16* __restrict__ out) {
    __shared__ __align__(16) u16 Qs[64 * 40];       // 5120 B
    __shared__ __align__(16) u16 Ks[2][64 * 40];    // 10240 B
    __shared__ __align__(16) u32 VtW[2][32 * 36];   // V^T packed dwords, 9216 B
    __shared__ float Tt[64];
    __shared__ float Ss[32];
    int b = blockIdx.z, h = blockIdx.y, q0 = blockIdx.x * 64;
    int tid = threadIdx.x, w = tid >> 6, lane = tid & 63, ln = lane & 15, quad = lane >> 4;
    long bh = b * 8 + h;
    const u16* qb = qr + bh * 32768;
    const u16* kb = kr + bh * 32768;
    const u16* vb = vr + bh * 32768;
    float dec = decay_l2(h);
    {   // stage Q
        int row = tid >> 2, seg = tid & 3;
        *(int4*)&Qs[row * 40 + seg * 8] = *(const int4*)&qb[(q0 + row) * 32 + seg * 8];
    }
    if (tid < 63) Tt[tid] = exp2f(dec * (float)tid);
    // staging geometry
    int krow = tid >> 2, kseg = tid & 3;
    int vp = tid >> 3, vseg = tid & 7;
    int4 kreg = *(const int4*)&kb[(long)krow * 32 + kseg * 8];
    int2 v0 = *(const int2*)&vb[(long)(vp * 2) * 32 + vseg * 4];
    int2 v1 = *(const int2*)&vb[(long)(vp * 2 + 1) * 32 + vseg * 4];
    __syncthreads();   // Qs + Tt ready
    bf16x8 aq = *(const bf16x8*)&Qs[(w * 16 + ln) * 40 + quad * 8];   // Q B-frag
    int q = q0 + w * 16 + ln;
    int q1i = q >> 5, q2i = q & 31;
    float bt[2][4];
#pragma unroll
    for (int s2 = 0; s2 < 2; s2++)
#pragma unroll
        for (int r = 0; r < 4; r++)
            bt[s2][r] = Tt[abs(q2i - (s2 * 16 + quad * 4 + r))];
    if (tid < 32) {
        float s = 0.0f;
#pragma unroll
        for (int b2 = 0; b2 < 32; b2++) s += Tt[abs(tid - b2)];
        Ss[tid] = s;
    }
    // write tile 0 to buf 0, prefetch tile 1
    *(int4*)&Ks[0][krow * 40 + kseg * 8] = kreg;
    VtW[0][(vseg * 4 + 0) * 36 + vp] = __builtin_amdgcn_perm(v1.x, v0.x, 0x05040100u);
    VtW[0][(vseg * 4 + 1) * 36 + vp] = __builtin_amdgcn_perm(v1.x, v0.x, 0x07060302u);
    VtW[0][(vseg * 4 + 2) * 36 + vp] = __builtin_amdgcn_perm(v1.y, v0.y, 0x05040100u);
    VtW[0][(vseg * 4 + 3) * 36 + vp] = __builtin_amdgcn_perm(v1.y, v0.y, 0x07060302u);
    kreg = *(const int4*)&kb[(long)(64 + krow) * 32 + kseg * 8];
    v0 = *(const int2*)&vb[(long)(64 + vp * 2) * 32 + vseg * 4];
    v1 = *(const int2*)&vb[(long)(64 + vp * 2 + 1) * 32 + vseg * 4];
    __syncthreads();   // Ss + buf0 ready
    float rqv = rsqrtf(Ss[q1i] * Ss[q2i]);
    f32x4 accO0 = {}, accO1 = {};
    float den = 0.0f;
    for (int kt = 0; kt < 16; kt++) {
        int cur = kt & 1;
        float a0 = Tt[abs(q1i - 2 * kt)] * rqv;
        float a1 = Tt[abs(q1i - 2 * kt - 1)] * rqv;
        const u16* ksb = &Ks[cur][0];
        const u32* vtb = &VtW[cur][0];
#pragma unroll
        for (int nt = 0; nt < 4; nt++) {
            bf16x8 ak = *(const bf16x8*)&ksb[(nt * 16 + ln) * 40 + quad * 8];
            f32x4 s = mfma16(ak, aq, (f32x4){0.f, 0.f, 0.f, 0.f});   // S^T rows kk, col q
            float aa = (nt & 2) ? a1 : a0;
            float p0 = s[0] * aa * bt[nt & 1][0];
            float p1 = s[1] * aa * bt[nt & 1][1];
            float p2 = s[2] * aa * bt[nt & 1][2];
            float p3 = s[3] * aa * bt[nt & 1][3];
            den += fabsf(p0); den += fabsf(p1); den += fabsf(p2); den += fabsf(p3);
            // P^T fragment stays in registers: B-frag of K=16 MFMA = C-layout (!)
            u32 blo = pack_bf16(p0, p1), bhi = pack_bf16(p2, p3);
            u64 bb = ((u64)bhi << 32) | blo;
            u64 av0 = *(const u64*)&vtb[ln * 36 + nt * 8 + quad * 2];
            u64 av1 = *(const u64*)&vtb[(16 + ln) * 36 + nt * 8 + quad * 2];
            accO0 = mfma_k16(av0, bb, accO0);   // O^T rows d=quad*4+r, col q
            accO1 = mfma_k16(av1, bb, accO1);   // d = 16 + quad*4+r
        }
        if (kt < 15) {
            int nb = 1 - cur;
            *(int4*)&Ks[nb][krow * 40 + kseg * 8] = kreg;
            VtW[nb][(vseg * 4 + 0) * 36 + vp] = __builtin_amdgcn_perm(v1.x, v0.x, 0x05040100u);
            VtW[nb][(vseg * 4 + 1) * 36 + vp] = __builtin_amdgcn_perm(v1.x, v0.x, 0x07060302u);
            VtW[nb][(vseg * 4 + 2) * 36 + vp] = __builtin_amdgcn_perm(v1.y, v0.y, 0x05040100u);
            VtW[nb][(vseg * 4 + 3) * 36 + vp] = __builtin_amdgcn_perm(v1.y, v0.y, 0x07060302u);
            if (kt < 14) {
                int t2 = (kt + 2) * 64;
                kreg = *(const int4*)&kb[(long)(t2 + krow) * 32 + kseg * 8];
                v0 = *(const int2*)&vb[(long)(t2 + vp * 2) * 32 + vseg * 4];
                v1 = *(const int2*)&vb[(long)(t2 + vp * 2 + 1) * 32 + vseg * 4];
            }
            __syncthreads();
        }
    }
    // reduce den over quads (lanes ln, 16+ln, 32+ln, 48+ln share col q)
    den += __shfl_xor(den, 16);
    den += __shfl_xor(den, 32);
    float id = 1.0f / fminf(fmaxf(den, 1.0f), 50000.0f);
    float o[8];
#pragma unroll
    for (int r = 0; r < 4; r++) { o[r] = accO0[r] * id; o[4 + r] = accO1[r] * id; }
    float s1 = 0.0f, s2 = 0.0f;
#pragma unroll
    for (int i = 0; i < 8; i++) { s1 += o[i]; s2 += o[i] * o[i]; }
    s1 += __shfl_xor(s1, 16); s1 += __shfl_xor(s1, 32);
    s2 += __shfl_xor(s2, 16); s2 += __shfl_xor(s2, 32);
    float mean = s1 * (1.0f / 32.0f);
    float var = s2 * (1.0f / 32.0f) - mean * mean;
    float rstd = rsqrtf(var + 1e-5f);
    float xg[8];
#pragma unroll
    for (int nv = 0; nv < 2; nv++)
#pragma unroll
        for (int r = 0; r < 4; r++) {
            int d = nv * 16 + quad * 4 + r;
            float xv = (o[nv * 4 + r] - mean) * rstd * lng[d] + lnb[d];
            xg[nv * 4 + r] = 0.5f * xv * (1.0f + erff(xv * 0.70710678118654752f));
        }
    u16* orow = out + ((long)(b * 1024 + q)) * 256 + h * 32;
    int2 st0, st1;
    st0.x = (int)pack_bf16(xg[0], xg[1]); st0.y = (int)pack_bf16(xg[2], xg[3]);
    st1.x = (int)pack_bf16(xg[4], xg[5]); st1.y = (int)pack_bf16(xg[6], xg[7]);
    *(int2*)&orow[quad * 4] = st0;
    *(int2*)&orow[16 + quad * 4] = st1;
}

extern "C" void kernel_launch(void* const* d_in, const int* in_sizes, int n_in,
                              void* d_out, int out_size, void* d_ws, size_t ws_size,
                              hipStream_t stream) {
    const float* x   = (const float*)d_in[0];
    const float* Wq  = (const float*)d_in[1];
    const float* Wk  = (const float*)d_in[2];
    const float* Wv  = (const float*)d_in[3];
    const float* Wo  = (const float*)d_in[4];
    const float* lng = (const float*)d_in[5];
    const float* lnb = (const float*)d_in[6];
    float* outp = (float*)d_out;

    u16* qr    = (u16*)d_ws;            // [B][H][L][32] bf16, 4 MB
    u16* kr    = qr + 2097152;
    u16* vr    = kr + 2097152;
    u16* attnb = vr + 2097152;          // [B*L][256] bf16, 4 MB
    float2* tc = (float2*)(attnb + 2097152);   // [L][32], 256 KB

    tc_kernel<<<128, 256, 0, stream>>>(tc);
    gemm_bt_kernel<1><<<dim3(4, 128, 3), 256, 0, stream>>>(x, Wq, Wk, Wv, tc, qr, kr, vr, nullptr, 0);
    attn_kernel<<<dim3(16, 8, 8), 256, 0, stream>>>(qr, kr, vr, lng, lnb, attnb);
    gemm_bt_kernel<0><<<dim3(4, 128, 1), 256, 0, stream>>>(attnb, Wo, Wo, Wo, tc, nullptr, nullptr, nullptr, outp, 3);
}

// Round 8
// 113.547 us; speedup vs baseline: 1.1819x; 1.0609x over previous
//
#include <hip/hip_runtime.h>
#include <math.h>

typedef unsigned short u16;
typedef unsigned int u32;
typedef unsigned long long u64;
typedef __bf16 bf16x8 __attribute__((ext_vector_type(8)));
typedef short s16x4 __attribute__((ext_vector_type(4)));
typedef float f32x4 __attribute__((ext_vector_type(4)));

#define SCALING 0.17677669529663687f   // 32^-0.5
#define LOG2E 1.44269504088896f
#define LOG2_10000 13.287712379549449f

__device__ __forceinline__ u16 f2bf(float f) {
    u32 u; __builtin_memcpy(&u, &f, 4);
    u = u + 0x7FFFu + ((u >> 16) & 1u);
    return (u16)(u >> 16);
}
__device__ __forceinline__ u32 fbits(float f) {
    u32 u; __builtin_memcpy(&u, &f, 4); return u;
}
// pack two f32 -> (bf16(lo) | bf16(hi)<<16)
__device__ __forceinline__ u32 pack_bf16(float lo, float hi) {
#if __has_builtin(__builtin_amdgcn_cvt_pk_bf16_f32)
    typedef __bf16 bf16x2_t __attribute__((ext_vector_type(2)));
    bf16x2_t r = __builtin_amdgcn_cvt_pk_bf16_f32(lo, hi);
    u32 u; __builtin_memcpy(&u, &r, 4); return u;
#else
    return __builtin_amdgcn_perm(fbits(hi) + 0x8000u, fbits(lo) + 0x8000u, 0x07060302u);
#endif
}
__device__ __forceinline__ f32x4 mfma16(bf16x8 a, bf16x8 b, f32x4 c) {
    return __builtin_amdgcn_mfma_f32_16x16x32_bf16(a, b, c, 0, 0, 0);
}
// K=16 bf16 MFMA: 4 bf16 per lane per operand (2 VGPRs)
__device__ __forceinline__ f32x4 mfma_k16(u64 a, u64 b, f32x4 c) {
#if __has_builtin(__builtin_amdgcn_mfma_f32_16x16x16bf16_1k)
    s16x4 av, bv;
    __builtin_memcpy(&av, &a, 8); __builtin_memcpy(&bv, &b, 8);
    return __builtin_amdgcn_mfma_f32_16x16x16bf16_1k(av, bv, c, 0, 0, 0);
#elif __has_builtin(__builtin_amdgcn_mfma_f32_16x16x16_bf16)
    typedef __bf16 bf16x4_t __attribute__((ext_vector_type(4)));
    bf16x4_t av, bv;
    __builtin_memcpy(&av, &a, 8); __builtin_memcpy(&bv, &b, 8);
    return __builtin_amdgcn_mfma_f32_16x16x16_bf16(av, bv, c, 0, 0, 0);
#else
    f32x4 d = c;
    asm volatile("v_mfma_f32_16x16x16_bf16 %0, %1, %2, %0\n\ts_nop 4"
                 : "+v"(d) : "v"(a), "v"(b));
    return d;
#endif
}
__device__ __forceinline__ float decay_l2(int h) {
    return logf(1.0f - exp2f(-2.0f - 0.625f * (float)h)) * LOG2E;
}

// ---- prep: x->bf16 (1024 blk), W->bf16 (128 blk), theta table (128 blk) ------
__global__ __launch_bounds__(256) void prep_kernel(
    const float* __restrict__ x,
    const float* __restrict__ Wq, const float* __restrict__ Wk,
    const float* __restrict__ Wv, const float* __restrict__ Wo,
    u16* __restrict__ xb, u16* __restrict__ wb, float2* __restrict__ tc) {
    int bid = blockIdx.x;
    if (bid >= 1152) {   // tc[l*32+d] = (cos, d odd? sin : -sin)
        int idx = (bid - 1152) * 256 + threadIdx.x;   // 0..32767
        int l = idx >> 5, d = idx & 31;
        float ang = exp2f(-LOG2_10000 * (1.0f / 15.0f) * (float)(d >> 1));
        float idl = (float)((l >> 5) + (l & 31));
        float sv, cv;
        __sincosf(idl * ang, &sv, &cv);
        tc[idx] = make_float2(cv, (d & 1) ? sv : -sv);
        return;
    }
    const float* src; u16* dst; int off;
    if (bid < 1024) { src = x; dst = xb; off = bid * 2048; }
    else {
        int wsel = (bid - 1024) >> 5;
        src = (wsel == 0) ? Wq : (wsel == 1) ? Wk : (wsel == 2) ? Wv : Wo;
        dst = wb + wsel * 65536;
        off = ((bid - 1024) & 31) * 2048;
    }
    int i = off + threadIdx.x * 8;
    float4 a = *(const float4*)&src[i];
    float4 b = *(const float4*)&src[i + 4];
    int4 t;
    t.x = (int)pack_bf16(a.x, a.y); t.y = (int)pack_bf16(a.z, a.w);
    t.z = (int)pack_bf16(b.x, b.y); t.w = (int)pack_bf16(b.z, b.w);
    *(int4*)&dst[i] = t;
}

// ---------------- GEMM C[i][e] = sum_j A[i][j] W[e][j]  (all bf16 in) ---------
// modes: 0=q (theta-shift), 1=k (scale+shift), 2=v, 3=plain f32 out
__global__ __launch_bounds__(256) void gemm_bt_kernel(
    const u16* __restrict__ A, const u16* __restrict__ Wb,
    const float2* __restrict__ tc,
    u16* __restrict__ O0, u16* __restrict__ O1, u16* __restrict__ O2,
    float* __restrict__ Of, int mode_base) {
    __shared__ __align__(16) u16 As[64 * 136];
    __shared__ __align__(16) u16 Ws[64 * 136];
    int z = blockIdx.z;
    const u16* W = Wb + z * 65536;
    u16* O = (z == 0) ? O0 : (z == 1) ? O1 : O2;
    int mode = mode_base + z;
    int n0 = blockIdx.x * 64, r0 = blockIdx.y * 64;   // n fast => A row-block L2 reuse
    int tid = threadIdx.x;
    int w = tid >> 6, lane = tid & 63, ln = lane & 15, quad = lane >> 4;
    f32x4 acc[4] = {};
#pragma unroll
    for (int ch = 0; ch < 2; ch++) {
        int k0 = ch * 128;
        if (ch) __syncthreads();
#pragma unroll
        for (int i = 0; i < 4; i++) {
            int c = tid + i * 256;
            int row = c >> 4, seg = c & 15;
            *(int4*)&As[row * 136 + seg * 8] = *(const int4*)&A[(long)(r0 + row) * 256 + k0 + seg * 8];
            *(int4*)&Ws[row * 136 + seg * 8] = *(const int4*)&W[(long)(n0 + row) * 256 + k0 + seg * 8];
        }
        __syncthreads();
#pragma unroll
        for (int kt = 0; kt < 4; kt++) {
            bf16x8 a = *(const bf16x8*)&As[(w * 16 + ln) * 136 + kt * 32 + quad * 8];
#pragma unroll
            for (int nt = 0; nt < 4; nt++) {
                bf16x8 b = *(const bf16x8*)&Ws[(nt * 16 + ln) * 136 + kt * 32 + quad * 8];
                acc[nt] = mfma16(a, b, acc[nt]);
            }
        }
    }
    int rowg = r0 + w * 16 + quad * 4;   // C row = quad*4 + reg
    if (mode == 3) {
#pragma unroll
        for (int nt = 0; nt < 4; nt++) {
            int e = n0 + nt * 16 + ln;
#pragma unroll
            for (int r = 0; r < 4; r++)
                Of[(long)(rowg + r) * 256 + e] = acc[nt][r];
        }
        return;
    }
    float scl = (mode == 1) ? SCALING : 1.0f;
#pragma unroll
    for (int nt = 0; nt < 4; nt++) {
        int e = n0 + nt * 16 + ln;
        int d = e & 31, hh = e >> 5;
#pragma unroll
        for (int r = 0; r < 4; r++) {
            int gi = rowg + r;
            int b = gi >> 10, l = gi & 1023;
            float v = acc[nt][r] * scl;
            float p = __shfl_xor(v, 1);   // partner col e^1, same row
            float res;
            if (mode == 2) {
                res = v;
            } else {
                float2 sc = tc[l * 32 + d];
                res = v * sc.x + p * sc.y;
            }
            O[(((long)(b * 8 + hh)) * 1024 + l) * 32 + d] = f2bf(res);
        }
    }
}

// ---- fused retention + LN + GELU: 128-q tile, 8 waves, register-P K=16 PV ----
__global__ __launch_bounds__(512) void attn_kernel(
    const u16* __restrict__ qr, const u16* __restrict__ kr, const u16* __restrict__ vr,
    const float* __restrict__ lng, const float* __restrict__ lnb,
    u16* __restrict__ out) {
    __shared__ __align__(16) u16 Qs[128 * 40];      // 10240 B
    __shared__ __align__(16) u16 Ks[2][64 * 40];    // 10240 B
    __shared__ __align__(16) u32 VtW[2][32 * 36];   // V^T packed dwords, 9216 B
    __shared__ float Tt[64];
    __shared__ float Ss[32];
    int b = blockIdx.z, h = blockIdx.y, q0 = blockIdx.x * 128;
    int tid = threadIdx.x, w = tid >> 6, lane = tid & 63, ln = lane & 15, quad = lane >> 4;
    long bh = b * 8 + h;
    const u16* qb = qr + bh * 32768;
    const u16* kb = kr + bh * 32768;
    const u16* vb = vr + bh * 32768;
    float dec = decay_l2(h);
    {   // stage Q (128 rows, 512 threads)
        int row = tid >> 2, seg = tid & 3;
        *(int4*)&Qs[row * 40 + seg * 8] = *(const int4*)&qb[(q0 + row) * 32 + seg * 8];
    }
    if (tid < 63) Tt[tid] = exp2f(dec * (float)tid);
    // staging duties: waves 0-3 stage K, waves 4-7 stage V
    bool isK = (tid < 256);
    int krow = (tid & 255) >> 2, kseg = tid & 3;
    int vt = tid & 255, vp = vt >> 3, vseg = vt & 7;
    int4 kreg; int2 v0, v1;
    if (isK) {
        kreg = *(const int4*)&kb[(long)krow * 32 + kseg * 8];
    } else {
        v0 = *(const int2*)&vb[(long)(vp * 2) * 32 + vseg * 4];
        v1 = *(const int2*)&vb[(long)(vp * 2 + 1) * 32 + vseg * 4];
    }
    __syncthreads();   // Qs + Tt ready
    bf16x8 aq = *(const bf16x8*)&Qs[(w * 16 + ln) * 40 + quad * 8];   // Q B-frag
    int q = q0 + w * 16 + ln;
    int q1i = q >> 5, q2i = q & 31;
    if (tid < 32) {
        float s = 0.0f;
#pragma unroll
        for (int b2 = 0; b2 < 32; b2++) s += Tt[abs(tid - b2)];
        Ss[tid] = s;
    }
    // write tile 0 to buf 0, prefetch tile 1
    if (isK) {
        *(int4*)&Ks[0][krow * 40 + kseg * 8] = kreg;
        kreg = *(const int4*)&kb[(long)(64 + krow) * 32 + kseg * 8];
    } else {
        VtW[0][(vseg * 4 + 0) * 36 + vp] = __builtin_amdgcn_perm(v1.x, v0.x, 0x05040100u);
        VtW[0][(vseg * 4 + 1) * 36 + vp] = __builtin_amdgcn_perm(v1.x, v0.x, 0x07060302u);
        VtW[0][(vseg * 4 + 2) * 36 + vp] = __builtin_amdgcn_perm(v1.y, v0.y, 0x05040100u);
        VtW[0][(vseg * 4 + 3) * 36 + vp] = __builtin_amdgcn_perm(v1.y, v0.y, 0x07060302u);
        v0 = *(const int2*)&vb[(long)(64 + vp * 2) * 32 + vseg * 4];
        v1 = *(const int2*)&vb[(long)(64 + vp * 2 + 1) * 32 + vseg * 4];
    }
    __syncthreads();   // Ss + buf0 ready
    float rqv = rsqrtf(Ss[q1i] * Ss[q2i]);
    float bt[2][4];
#pragma unroll
    for (int s2 = 0; s2 < 2; s2++)
#pragma unroll
        for (int r = 0; r < 4; r++)
            bt[s2][r] = Tt[abs(q2i - (s2 * 16 + quad * 4 + r))] * rqv;   // rqv folded
    f32x4 accO0 = {}, accO1 = {};
    float den = 0.0f;
    for (int kt = 0; kt < 16; kt++) {
        int cur = kt & 1;
        float a0 = Tt[abs(q1i - 2 * kt)];
        float a1 = Tt[abs(q1i - 2 * kt - 1)];
        const u16* ksb = &Ks[cur][0];
        const u32* vtb = &VtW[cur][0];
#pragma unroll
        for (int nt = 0; nt < 4; nt++) {
            bf16x8 ak = *(const bf16x8*)&ksb[(nt * 16 + ln) * 40 + quad * 8];
            f32x4 s = mfma16(ak, aq, (f32x4){0.f, 0.f, 0.f, 0.f});   // S^T rows kk, col q
            float aa = (nt & 2) ? a1 : a0;
            float p0 = s[0] * aa * bt[nt & 1][0];
            float p1 = s[1] * aa * bt[nt & 1][1];
            float p2 = s[2] * aa * bt[nt & 1][2];
            float p3 = s[3] * aa * bt[nt & 1][3];
            den += fabsf(p0); den += fabsf(p1); den += fabsf(p2); den += fabsf(p3);
            // P^T fragment stays in registers: B-frag of K=16 MFMA = C-layout
            u32 blo = pack_bf16(p0, p1), bhi = pack_bf16(p2, p3);
            u64 bb = ((u64)bhi << 32) | blo;
            u64 av0 = *(const u64*)&vtb[ln * 36 + nt * 8 + quad * 2];
            u64 av1 = *(const u64*)&vtb[(16 + ln) * 36 + nt * 8 + quad * 2];
            accO0 = mfma_k16(av0, bb, accO0);   // O^T rows d=quad*4+r, col q
            accO1 = mfma_k16(av1, bb, accO1);   // d = 16 + quad*4+r
        }
        if (kt < 15) {
            int nb = 1 - cur;
            if (isK) {
                *(int4*)&Ks[nb][krow * 40 + kseg * 8] = kreg;
                if (kt < 14)
                    kreg = *(const int4*)&kb[(long)((kt + 2) * 64 + krow) * 32 + kseg * 8];
            } else {
                VtW[nb][(vseg * 4 + 0) * 36 + vp] = __builtin_amdgcn_perm(v1.x, v0.x, 0x05040100u);
                VtW[nb][(vseg * 4 + 1) * 36 + vp] = __builtin_amdgcn_perm(v1.x, v0.x, 0x07060302u);
                VtW[nb][(vseg * 4 + 2) * 36 + vp] = __builtin_amdgcn_perm(v1.y, v0.y, 0x05040100u);
                VtW[nb][(vseg * 4 + 3) * 36 + vp] = __builtin_amdgcn_perm(v1.y, v0.y, 0x07060302u);
                if (kt < 14) {
                    int t2 = (kt + 2) * 64;
                    v0 = *(const int2*)&vb[(long)(t2 + vp * 2) * 32 + vseg * 4];
                    v1 = *(const int2*)&vb[(long)(t2 + vp * 2 + 1) * 32 + vseg * 4];
                }
            }
            __syncthreads();
        }
    }
    // reduce den over quads (lanes ln, 16+ln, 32+ln, 48+ln share col q)
    den += __shfl_xor(den, 16);
    den += __shfl_xor(den, 32);
    float id = 1.0f / fminf(fmaxf(den, 1.0f), 50000.0f);
    float o[8];
#pragma unroll
    for (int r = 0; r < 4; r++) { o[r] = accO0[r] * id; o[4 + r] = accO1[r] * id; }
    float s1 = 0.0f, s2 = 0.0f;
#pragma unroll
    for (int i = 0; i < 8; i++) { s1 += o[i]; s2 += o[i] * o[i]; }
    s1 += __shfl_xor(s1, 16); s1 += __shfl_xor(s1, 32);
    s2 += __shfl_xor(s2, 16); s2 += __shfl_xor(s2, 32);
    float mean = s1 * (1.0f / 32.0f);
    float var = s2 * (1.0f / 32.0f) - mean * mean;
    float rstd = rsqrtf(var + 1e-5f);
    float xg[8];
#pragma unroll
    for (int nv = 0; nv < 2; nv++)
#pragma unroll
        for (int r = 0; r < 4; r++) {
            int d = nv * 16 + quad * 4 + r;
            float xv = (o[nv * 4 + r] - mean) * rstd * lng[d] + lnb[d];
            xg[nv * 4 + r] = 0.5f * xv * (1.0f + erff(xv * 0.70710678118654752f));
        }
    u16* orow = out + ((long)(b * 1024 + q)) * 256 + h * 32;
    int2 st0, st1;
    st0.x = (int)pack_bf16(xg[0], xg[1]); st0.y = (int)pack_bf16(xg[2], xg[3]);
    st1.x = (int)pack_bf16(xg[4], xg[5]); st1.y = (int)pack_bf16(xg[6], xg[7]);
    *(int2*)&orow[quad * 4] = st0;
    *(int2*)&orow[16 + quad * 4] = st1;
}

extern "C" void kernel_launch(void* const* d_in, const int* in_sizes, int n_in,
                              void* d_out, int out_size, void* d_ws, size_t ws_size,
                              hipStream_t stream) {
    const float* x   = (const float*)d_in[0];
    const float* Wq  = (const float*)d_in[1];
    const float* Wk  = (const float*)d_in[2];
    const float* Wv  = (const float*)d_in[3];
    const float* Wo  = (const float*)d_in[4];
    const float* lng = (const float*)d_in[5];
    const float* lnb = (const float*)d_in[6];
    float* outp = (float*)d_out;

    u16* xb    = (u16*)d_ws;            // [B*L][256] bf16, 4 MB
    u16* wb    = xb + 2097152;          // Wq|Wk|Wv|Wo bf16, 0.5 MB
    u16* qr    = wb + 262144;           // [B][H][L][32] bf16, 4 MB
    u16* kr    = qr + 2097152;
    u16* vr    = kr + 2097152;
    u16* attnb = vr + 2097152;          // [B*L][256] bf16, 4 MB
    float2* tc = (float2*)(attnb + 2097152);   // [L][32], 256 KB

    prep_kernel<<<1280, 256, 0, stream>>>(x, Wq, Wk, Wv, Wo, xb, wb, tc);
    gemm_bt_kernel<<<dim3(4, 128, 3), 256, 0, stream>>>(xb, wb, tc, qr, kr, vr, nullptr, 0);
    attn_kernel<<<dim3(8, 8, 8), 512, 0, stream>>>(qr, kr, vr, lng, lnb, attnb);
    gemm_bt_kernel<<<dim3(4, 128, 1), 256, 0, stream>>>(attnb, wb + 3 * 65536, tc, nullptr, nullptr, nullptr, outp, 3);
}